// Round 2
// baseline (266.674 us; speedup 1.0000x reference)
//
#include <hip/hip_runtime.h>
#include <hip/hip_bf16.h>

// ---------------------------------------------------------------------------
// AttentionBlock: B=8, L=1024, C=1024, H=8, ch=128.
// fp32 I/O, bf16 MFMA internal.  Head split is a free flat reinterpret.
// R8 lesson: scattered 2B global stores amplify HBM writes ~10x.
// R9 lesson: launch_bounds floors past VGPR need -> scratch spills (1 GB HBM).
// R11: attn blocks widened to 512 thr / 8 waves sharing one K/V staging.
// R12: gemm_qkv rebuilt as 256x128 tile, 512 thr, double-buffered LDS with
//      counted vmcnt(6) pipeline (T3+T4), setprio around MFMA (T5), XCD
//      swizzle (T1).  Old structure was 0-deep (__syncthreads drains vmcnt
//      every K-tile) -> MfmaUtil 30%.
// R13: resubmit of R12 (container failed twice = infra flake; kernel
//      re-audited: no divergent barriers, bounds ok, pipeline hazard-free).
// ---------------------------------------------------------------------------

typedef __attribute__((ext_vector_type(8))) short short8;
typedef __attribute__((ext_vector_type(4))) float f32x4;

#define QK_SCALE 0.29730177875068026f  // 128^-0.25

__device__ __forceinline__ float bf2f(ushort u) {
    union { float f; unsigned int i; } c; c.i = ((unsigned int)u) << 16; return c.f;
}
__device__ __forceinline__ ushort f2bf(float f) {
    union { float f; unsigned int i; } c; c.f = f;
    unsigned int x = c.i;
    return (ushort)((x + 0x7FFFu + ((x >> 16) & 1u)) >> 16);  // RNE
}

// async 16B global->LDS (m97; LDS dest must be wave-uniform base + lane*16)
__device__ __forceinline__ void gload_lds16(const ushort* g, ushort* l) {
    __builtin_amdgcn_global_load_lds(
        (const __attribute__((address_space(1))) unsigned int*)g,
        (__attribute__((address_space(3))) unsigned int*)l, 16, 0, 0);
}

// ---------------------------------------------------------------------------
// Prep kernel: LN row-per-wave (blocks 0..2047, 4 rows/block, no barriers)
// + w_qkv transpose tiles (2048..5119) + w_out transpose (5120..6143).
// ---------------------------------------------------------------------------
__global__ __launch_bounds__(256) void prep_kernel(
    const float* __restrict__ x, const float* __restrict__ g,
    const float* __restrict__ b, ushort* __restrict__ xn,
    const float* __restrict__ w_qkv, ushort* __restrict__ wqkvT,
    const float* __restrict__ w_out, ushort* __restrict__ woutT) {
    __shared__ ushort t[32][33];
    int bid = blockIdx.x;
    int tid = threadIdx.x;
    if (bid < 2048) {
        // ---- LayerNorm: one row per wave ----
        int w = tid >> 6, lane = tid & 63;
        int row = bid * 4 + w;
        const float* xr = x + (size_t)row * 1024;
        float v[4][4];
        float s1 = 0.f, s2 = 0.f;
#pragma unroll
        for (int j = 0; j < 4; j++) {
            float4 t4 = *(const float4*)(xr + lane * 4 + j * 256);
            v[j][0] = t4.x; v[j][1] = t4.y; v[j][2] = t4.z; v[j][3] = t4.w;
#pragma unroll
            for (int e = 0; e < 4; e++) { s1 += v[j][e]; s2 += v[j][e] * v[j][e]; }
        }
#pragma unroll
        for (int m = 32; m >= 1; m >>= 1) { s1 += __shfl_xor(s1, m); s2 += __shfl_xor(s2, m); }
        float mu = s1 * (1.0f / 1024.0f);
        float var = s2 * (1.0f / 1024.0f) - mu * mu;
        float rs = rsqrtf(var + 1e-5f);
#pragma unroll
        for (int j = 0; j < 4; j++) {
            int c0 = lane * 4 + j * 256;
            float4 gg = *(const float4*)(g + c0);
            float4 bb = *(const float4*)(b + c0);
            float gA[4] = {gg.x, gg.y, gg.z, gg.w};
            float bA[4] = {bb.x, bb.y, bb.z, bb.w};
            ushort o[4];
#pragma unroll
            for (int e = 0; e < 4; e++) o[e] = f2bf((v[j][e] - mu) * rs * gA[e] + bA[e]);
            uint2 pk;
            pk.x = (uint)o[0] | ((uint)o[1] << 16);
            pk.y = (uint)o[2] | ((uint)o[3] << 16);
            *(uint2*)(xn + (size_t)row * 1024 + c0) = pk;
        }
    } else {
        // ---- weight transpose tile ----
        const float* in; ushort* out; int R, Cc, bx, by;
        if (bid < 5120) {
            int tt = bid - 2048;
            in = w_qkv; out = wqkvT; R = 1024; Cc = 3072;
            bx = (tt % 96) * 32; by = (tt / 96) * 32;
        } else {
            int tt = bid - 5120;
            in = w_out; out = woutT; R = 1024; Cc = 1024;
            bx = (tt % 32) * 32; by = (tt / 32) * 32;
        }
        int tx = tid & 31, ty = tid >> 5;
#pragma unroll
        for (int j = 0; j < 32; j += 8)
            t[ty + j][tx] = f2bf(in[(size_t)(by + ty + j) * Cc + bx + tx]);
        __syncthreads();
#pragma unroll
        for (int j = 0; j < 32; j += 8)
            out[(size_t)(bx + ty + j) * R + by + tx] = t[tx][ty + j];
    }
}

// ---------------------------------------------------------------------------
// Per-head bf16 transpose: in [64][1024][128] -> out [64][128][1024]
// ---------------------------------------------------------------------------
__global__ __launch_bounds__(256) void transpose_head(
    const ushort* __restrict__ in, ushort* __restrict__ out) {
    __shared__ ushort t[32][33];
    int h = blockIdx.z;
    int j0 = blockIdx.y * 32;  // seq pos
    int d0 = blockIdx.x * 32;  // head dim
    int tx = threadIdx.x & 31, ty = threadIdx.x >> 5;
    const ushort* src = in + (size_t)h * 131072;
    ushort* dst = out + (size_t)h * 131072;
#pragma unroll
    for (int j = 0; j < 32; j += 8)
        t[ty + j][tx] = src[(size_t)(j0 + ty + j) * 128 + d0 + tx];
    __syncthreads();
#pragma unroll
    for (int j = 0; j < 32; j += 8)
        dst[(size_t)(d0 + ty + j) * 1024 + j0 + tx] = t[tx][ty + j];
}

// ---------------------------------------------------------------------------
// QKV GEMM R12: C[8192,3072] = A[8192,1024] @ Bt[3072,1024]^T.
// 256x128 tile, BK=64, 512 thr = 8 waves (4M x 2N, 64x64 per wave).
// LDS 96 KB: As[2][256x64] + Bs[2][128x64], double-buffered.
// Pipeline (2-deep, counted vmcnt -- T4):
//   prologue: stage K0->buf0, K1->buf1; vmcnt(6); barrier
//   iter t:   read 16 frags from buf[t&1]; MFMA kk0 (setprio);
//             lgkmcnt(0); barrier            <- buf[t&1] now free (all waves)
//             stage K(t+2)->buf[t&1];        <- 6 gloads, ~1.5 iters to land
//             MFMA kk1 (setprio);
//             vmcnt(6); barrier              <- K(t+1) landed, K(t+2) in flight
// Never drains vmcnt to 0 in steady state.  XOR-8 chunk swizzle (proven
// conflict-free, SQ_LDS_BANK_CONFLICT=0).  Grid 768 = 3 exact CU waves.
// ---------------------------------------------------------------------------
__device__ __forceinline__ void stage6(const ushort* __restrict__ Ab,
                                       const ushort* __restrict__ Bb, int t2,
                                       ushort* AsD, ushort* BsD, int tid) {
    const ushort* As_src = Ab + t2 * 64;
    const ushort* Bs_src = Bb + t2 * 64;
#pragma unroll
    for (int i = 0; i < 4; i++) {
        int lin = i * 512 + tid;             // 0..2047: 16B chunk id of A tile
        int r = lin >> 3, p = lin & 7;
        int l = p ^ (r & 7);                 // logical chunk at phys slot p
        gload_lds16(As_src + (size_t)r * 1024 + l * 8, &AsD[lin * 8]);
    }
#pragma unroll
    for (int i = 0; i < 2; i++) {
        int lin = i * 512 + tid;             // 0..1023: chunk id of B tile
        int r = lin >> 3, p = lin & 7;
        int l = p ^ (r & 7);
        gload_lds16(Bs_src + (size_t)r * 1024 + l * 8, &BsD[lin * 8]);
    }
}

__global__ __launch_bounds__(512, 2) void gemm_qkv(
    const ushort* __restrict__ A, const ushort* __restrict__ Bt,
    const float* __restrict__ bias, ushort* __restrict__ out0,
    ushort* __restrict__ out1, ushort* __restrict__ out2) {
    __shared__ __align__(16) ushort As[2][256 * 64];  // 64 KB
    __shared__ __align__(16) ushort Bs[2][128 * 64];  // 32 KB

    int tid = threadIdx.x;
    int lane = tid & 63, w = tid >> 6;       // 8 waves
    int l15 = lane & 15, q4 = lane >> 4;
    int wrM = (w >> 1) * 64;                 // wave M offset: 0/64/128/192
    int wcN = (w & 1) * 64;                  // wave N offset: 0/64

    // T1 XCD swizzle: 768 blocks, 96/XCD, contiguous in M within an XCD so
    // the XCD's ~3 B-panels (768 KB) stay L2-resident.
    int bid = blockIdx.x;
    int swz = (bid & 7) * 96 + (bid >> 3);   // bijective: 768 % 8 == 0
    int by = swz & 31;                       // M-tile 0..31
    int bx = swz >> 5;                       // N-tile 0..23
    int rowBase = by * 256, colBase = bx * 128;

    const ushort* Ab = A + (size_t)rowBase * 1024;
    const ushort* Bb = Bt + (size_t)colBase * 1024;

    f32x4 acc[4][4];
    f32x4 zero = {0.f, 0.f, 0.f, 0.f};
#pragma unroll
    for (int mi = 0; mi < 4; mi++)
#pragma unroll
        for (int ni = 0; ni < 4; ni++) acc[mi][ni] = zero;

    // prologue: fill both buffers, wait only for buf0 (K1 stays in flight)
    stage6(Ab, Bb, 0, &As[0][0], &Bs[0][0], tid);
    stage6(Ab, Bb, 1, &As[1][0], &Bs[1][0], tid);
    asm volatile("s_waitcnt vmcnt(6)" ::: "memory");
    __builtin_amdgcn_s_barrier();

    for (int t = 0; t < 16; ++t) {
        const int cur = t & 1;
        const ushort* Ac = &As[cur][0];
        const ushort* Bc = &Bs[cur][0];

        // ---- read all 16 fragments of this K-tile into registers ----
        short8 aF[4][2], bF[4][2];
#pragma unroll
        for (int kk = 0; kk < 2; kk++) {
#pragma unroll
            for (int mi = 0; mi < 4; mi++) {
                int r = wrM + mi * 16 + l15;
                aF[mi][kk] = *(const short8*)&Ac[r * 64 + ((kk * 4 + q4) ^ (r & 7)) * 8];
            }
#pragma unroll
            for (int ni = 0; ni < 4; ni++) {
                int r = wcN + ni * 16 + l15;
                bF[ni][kk] = *(const short8*)&Bc[r * 64 + ((kk * 4 + q4) ^ (r & 7)) * 8];
            }
        }

        // ---- MFMA kk=0 (compiler inserts partial lgkmcnt; kk1 reads fly) ----
        __builtin_amdgcn_s_setprio(1);
#pragma unroll
        for (int mi = 0; mi < 4; mi++)
#pragma unroll
            for (int ni = 0; ni < 4; ni++)
                acc[mi][ni] = __builtin_amdgcn_mfma_f32_16x16x32_bf16(
                    aF[mi][0], bF[ni][0], acc[mi][ni], 0, 0, 0);
        __builtin_amdgcn_s_setprio(0);

        // all 16 reads sampled -> buf[cur] free for restaging (block-wide)
        asm volatile("s_waitcnt lgkmcnt(0)" ::: "memory");
        __builtin_amdgcn_s_barrier();
        if (t < 14) stage6(Ab, Bb, t + 2, &As[cur][0], &Bs[cur][0], tid);

        // ---- MFMA kk=1 (hides the stage issue + in-flight loads) ----
        __builtin_amdgcn_s_setprio(1);
#pragma unroll
        for (int mi = 0; mi < 4; mi++)
#pragma unroll
            for (int ni = 0; ni < 4; ni++)
                acc[mi][ni] = __builtin_amdgcn_mfma_f32_16x16x32_bf16(
                    aF[mi][1], bF[ni][1], acc[mi][ni], 0, 0, 0);
        __builtin_amdgcn_s_setprio(0);

        if (t < 15) {
            if (t < 14) asm volatile("s_waitcnt vmcnt(6)" ::: "memory");
            else        asm volatile("s_waitcnt vmcnt(0)" ::: "memory");
            __builtin_amdgcn_s_barrier();
        }
    }

    // C layout: col = lane&15, row = (lane>>4)*4 + r  [m89/m91]
#pragma unroll
    for (int ni = 0; ni < 4; ni++) {
        int col = colBase + wcN + ni * 16 + l15;
        float bv = bias[col];
        float sc = (col < 2048) ? QK_SCALE : 1.0f;
        int bsel = col >> 10, cc = col & 1023;
        ushort* dst = (bsel == 0) ? out0 : ((bsel == 1) ? out1 : out2);
#pragma unroll
        for (int mi = 0; mi < 4; mi++) {
            f32x4 a = acc[mi][ni];
#pragma unroll
            for (int r = 0; r < 4; r++) {
                int row = rowBase + wrM + mi * 16 + q4 * 4 + r;
                dst[(size_t)row * 1024 + cc] = f2bf((a[r] + bv) * sc);
            }
        }
    }
}

// ---------------------------------------------------------------------------
// Out-proj GEMM: outf[M,1024] = A[M,1024] @ Bt[1024,1024]^T + bias + resid.
// 64x128 tile, BK=64, XOR-8 swizzle, grid (8,128)=1024 blocks, 24 KB LDS.
// (256,4) measured spill-free.
// ---------------------------------------------------------------------------
__global__ __launch_bounds__(256, 4) void gemm_out(
    const ushort* __restrict__ A, const ushort* __restrict__ Bt,
    const float* __restrict__ bias, const ushort* __restrict__ resid,
    float* __restrict__ outf) {
    const int K = 1024;
    __shared__ __align__(16) ushort As[64 * 64];    //  8 KB, 512 chunks
    __shared__ __align__(16) ushort Bs[128 * 64];   // 16 KB, 1024 chunks

    int tid = threadIdx.x;
    int lane = tid & 63, w = tid >> 6;
    int l15 = lane & 15, q4 = lane >> 4;
    int wr = (w >> 1) * 32, wc = (w & 1) * 64;
    int rowBase = blockIdx.y * 64, colBase = blockIdx.x * 128;

    const ushort* src[6]; ushort* dstp[6];
#pragma unroll
    for (int i = 0; i < 6; i++) {
        int id = i * 256 + w * 64 + lane;  // 0..1535
        if (id < 512) {
            int r = id >> 3, l = (id & 7) ^ ((id >> 3) & 7);
            src[i] = A + (size_t)(rowBase + r) * K + l * 8;
            dstp[i] = &As[id * 8];
        } else {
            int idb = id - 512;
            int r = idb >> 3, l = (idb & 7) ^ ((idb >> 3) & 7);
            src[i] = Bt + (size_t)(colBase + r) * K + l * 8;
            dstp[i] = &Bs[idb * 8];
        }
    }

    f32x4 acc[2][4];
    f32x4 zero = {0.f, 0.f, 0.f, 0.f};
#pragma unroll
    for (int mi = 0; mi < 2; mi++)
#pragma unroll
        for (int ni = 0; ni < 4; ni++) acc[mi][ni] = zero;

    for (int kt = 0; kt < 16; kt++) {
        __syncthreads();
#pragma unroll
        for (int i = 0; i < 6; i++) {
            gload_lds16(src[i], dstp[i]);
            src[i] += 64;
        }
        __syncthreads();

#pragma unroll
        for (int kk = 0; kk < 2; kk++) {
            short8 aF[2], bF[4];
#pragma unroll
            for (int mi = 0; mi < 2; mi++) {
                int r = wr + mi * 16 + l15;
                aF[mi] = *(const short8*)&As[r * 64 + ((kk * 4 + q4) ^ (r & 7)) * 8];
            }
#pragma unroll
            for (int ni = 0; ni < 4; ni++) {
                int r = wc + ni * 16 + l15;
                bF[ni] = *(const short8*)&Bs[r * 64 + ((kk * 4 + q4) ^ (r & 7)) * 8];
            }
#pragma unroll
            for (int mi = 0; mi < 2; mi++)
#pragma unroll
                for (int ni = 0; ni < 4; ni++)
                    acc[mi][ni] = __builtin_amdgcn_mfma_f32_16x16x32_bf16(
                        aF[mi], bF[ni], acc[mi][ni], 0, 0, 0);
        }
    }

#pragma unroll
    for (int ni = 0; ni < 4; ni++) {
        int col = colBase + wc + ni * 16 + l15;
        float bv = bias[col];
#pragma unroll
        for (int mi = 0; mi < 2; mi++) {
            f32x4 a = acc[mi][ni];
#pragma unroll
            for (int r = 0; r < 4; r++) {
                int row = rowBase + wr + mi * 16 + q4 * 4 + r;
                outf[(size_t)row * 1024 + col] =
                    a[r] + bv + bf2f(resid[(size_t)row * 1024 + col]);
            }
        }
    }
}

// ---------------------------------------------------------------------------
// Attention v7: one block = (head g, 128 q-rows); 8 waves x 16q; 512 thr.
// One K/V staging serves 2x the compute of v4: per-thread staging gloads
// halve (8->4/kt) and per-head K/V re-staging halves (8 q-blocks vs 16).
// LDS 48 KB (Ks 16K + Vt 16K + Ps 16K).  Per-wave math identical to v4.
//  - Ks [64 key][128 d], XOR-16 chunk swizzle, global_load_lds staged
//  - Vt [128 d][64 key], XOR-8 chunk swizzle, global_load_lds staged
//  - Ps [128 q][64 key], XOR-8 chunk swizzle, wave-private rows
// ---------------------------------------------------------------------------
__global__ __launch_bounds__(512) void attn_kernel(
    const ushort* __restrict__ qb, const ushort* __restrict__ kb,
    const ushort* __restrict__ vt, ushort* __restrict__ ob) {
    int g = blockIdx.x >> 3;       // head 0..63
    int qblk = blockIdx.x & 7;     // 128-row q block
    const ushort* Qh = qb + (size_t)g * 131072;
    const ushort* Kh = kb + (size_t)g * 131072;
    const ushort* Vh = vt + (size_t)g * 131072;  // [128 d][1024 key]

    __shared__ __align__(16) ushort Ks[64 * 128];   // 16 KB
    __shared__ __align__(16) ushort Vt[128 * 64];   // 16 KB
    __shared__ __align__(16) ushort Ps[128 * 64];   // 16 KB

    int tid = threadIdx.x, lane = tid & 63, w = tid >> 6;  // w in [0,8)
    int l15 = lane & 15, q4 = lane >> 4;
    int q0 = qblk * 128;

    // Q A-fragments: A[m=l15][k = ks*32 + q4*8 + j]
    short8 qf[4];
#pragma unroll
    for (int ks = 0; ks < 4; ks++)
        qf[ks] = *(const short8*)&Qh[(size_t)(q0 + w * 16 + l15) * 128 + ks * 32 + q4 * 8];

    f32x4 zero = {0.f, 0.f, 0.f, 0.f};
    f32x4 o[8];
#pragma unroll
    for (int ni = 0; ni < 8; ni++) o[ni] = zero;
    float plsum[4] = {0.f, 0.f, 0.f, 0.f};

    for (int kt = 0; kt < 16; kt++) {
        __syncthreads();
        // Ks: phys chunk p in key-row r holds logical chunk l = p ^ (r&15)
#pragma unroll
        for (int i = 0; i < 2; i++) {
            int linear = i * 512 + tid;          // 0..1023, wave-contiguous
            int r = linear >> 4, p = linear & 15;
            int l = p ^ (r & 15);
            gload_lds16(&Kh[(size_t)(kt * 64 + r) * 128 + l * 8], &Ks[linear * 8]);
        }
        // Vt: phys chunk p in d-row holds logical chunk c = p ^ (d&7)
#pragma unroll
        for (int i = 0; i < 2; i++) {
            int linear = i * 512 + tid;          // 0..1023
            int d = linear >> 3, p = linear & 7;
            int c = p ^ (d & 7);
            gload_lds16(&Vh[(size_t)d * 1024 + kt * 64 + c * 8], &Vt[linear * 8]);
        }
        __syncthreads();

        // S = Q K^T : 16q x 64key per wave
        f32x4 sacc[4];
#pragma unroll
        for (int ni = 0; ni < 4; ni++) sacc[ni] = zero;
#pragma unroll
        for (int ks = 0; ks < 4; ks++) {
#pragma unroll
            for (int ni = 0; ni < 4; ni++) {
                int r = ni * 16 + l15;
                int p = (ks * 4 + q4) ^ (r & 15);
                short8 bF = *(const short8*)&Ks[r * 128 + p * 8];
                sacc[ni] = __builtin_amdgcn_mfma_f32_16x16x32_bf16(
                    qf[ks], bF, sacc[ni], 0, 0, 0);
            }
        }

        // P = exp(S) -> Ps (swizzled); accumulate per-lane partial row sums
#pragma unroll
        for (int ni = 0; ni < 4; ni++) {
#pragma unroll
            for (int r = 0; r < 4; r++) {
                float pv = __expf(sacc[ni][r]);
                plsum[r] += pv;
                int qloc = w * 16 + q4 * 4 + r;       // wave-private rows
                int key = ni * 16 + l15;
                int pc = (key >> 3) ^ (qloc & 7);
                Ps[qloc * 64 + pc * 8 + (key & 7)] = f2bf(pv);
            }
        }

        // O += P V  (wave-private Ps rows; same-wave RAW handled by waitcnt)
#pragma unroll
        for (int ks2 = 0; ks2 < 2; ks2++) {
            int c = ks2 * 4 + q4;
            int row = w * 16 + l15;                   // row&7 == l15&7
            short8 aF = *(const short8*)&Ps[row * 64 + (c ^ (l15 & 7)) * 8];
#pragma unroll
            for (int ni = 0; ni < 8; ni++) {
                int d = ni * 16 + l15;
                short8 bF = *(const short8*)&Vt[d * 64 + (c ^ (d & 7)) * 8];
                o[ni] = __builtin_amdgcn_mfma_f32_16x16x32_bf16(aF, bF, o[ni], 0, 0, 0);
            }
        }
    }

    // row sums: reduce per-lane partials over the 16 l15-lanes
#pragma unroll
    for (int r = 0; r < 4; r++) {
#pragma unroll
        for (int m = 1; m < 16; m <<= 1) plsum[r] += __shfl_xor(plsum[r], m, 16);
    }
    float inv[4];
#pragma unroll
    for (int r = 0; r < 4; r++) inv[r] = 1.0f / plsum[r];
#pragma unroll
    for (int ni = 0; ni < 8; ni++)
#pragma unroll
        for (int r = 0; r < 4; r++) {
            int qrow = q0 + w * 16 + q4 * 4 + r;
            ob[(size_t)g * 131072 + (size_t)qrow * 128 + ni * 16 + l15] =
                f2bf(o[ni][r] * inv[r]);
        }
}

// ---------------------------------------------------------------------------
extern "C" void kernel_launch(void* const* d_in, const int* in_sizes, int n_in,
                              void* d_out, int out_size, void* d_ws, size_t ws_size,
                              hipStream_t stream) {
    const float* x     = (const float*)d_in[0];
    const float* ln_g  = (const float*)d_in[1];
    const float* ln_b  = (const float*)d_in[2];
    const float* w_qkv = (const float*)d_in[3];
    const float* b_qkv = (const float*)d_in[4];
    const float* w_out = (const float*)d_in[5];
    const float* b_out = (const float*)d_in[6];
    float* out = (float*)d_out;

    const size_t MC = 8192ull * 1024ull;  // 8.39M elems
    ushort* xn    = (ushort*)d_ws;
    ushort* wqkvT = xn + MC;
    ushort* woutT = wqkvT + 3072ull * 1024ull;
    ushort* qbuf  = woutT + 1024ull * 1024ull;
    ushort* kbuf  = qbuf + MC;
    ushort* vtbuf = kbuf + MC;        // V^T [64 heads][128 d][1024 seq]
    ushort* attnb = vtbuf + MC;       // scratch for raw V, then attn output
    // total: 46.14M ushorts = 92.3 MB (same layout as passing rounds 2-10)

    prep_kernel<<<6144, 256, 0, stream>>>(x, ln_g, ln_b, xn, w_qkv, wqkvT, w_out, woutT);
    // q,k -> qbuf,kbuf ; v -> attnb (scratch, row-major coalesced)
    gemm_qkv<<<768, 512, 0, stream>>>(xn, wqkvT, b_qkv, qbuf, kbuf, attnb);
    transpose_head<<<dim3(4, 32, 64), 256, 0, stream>>>(attnb, vtbuf);
    attn_kernel<<<512, 512, 0, stream>>>(qbuf, kbuf, vtbuf, attnb);
    gemm_out<<<dim3(8, 128), 256, 0, stream>>>(attnb, woutT, b_out, xn, out);
}

// Round 3
// 249.455 us; speedup vs baseline: 1.0690x; 1.0690x over previous
//
#include <hip/hip_runtime.h>
#include <hip/hip_bf16.h>

// ---------------------------------------------------------------------------
// AttentionBlock: B=8, L=1024, C=1024, H=8, ch=128.
// fp32 I/O, bf16 MFMA internal.  Head split is a free flat reinterpret.
// R8 lesson: scattered 2B global stores amplify HBM writes ~10x.
// R9 lesson: launch_bounds floors past VGPR need -> scratch spills (1 GB HBM).
// R11: attn blocks widened to 512 thr / 8 waves sharing one K/V staging.
// R12: gemm_qkv rebuilt as 256x128 tile, 512 thr, double-buffered LDS with
//      counted vmcnt(6) pipeline (T3+T4), setprio around MFMA (T5).
// R13 lesson (measured): swizzle (bid&7)*96+bid>>3 put M fast-varying per
//      XCD -> concurrent working set = whole 16.8MB A vs 4MB L2 -> FETCH
//      200MB (2.6x), gemm_qkv 83.5us fetch-bound at 2.44 TB/s.
// R14: XCD owns a contiguous 4-M-tile band (2MB A, L2-resident), sweeps N
//      fastest.  A fetched once globally, B once per XCD: ~70MB total.
// ---------------------------------------------------------------------------

typedef __attribute__((ext_vector_type(8))) short short8;
typedef __attribute__((ext_vector_type(4))) float f32x4;

#define QK_SCALE 0.29730177875068026f  // 128^-0.25

__device__ __forceinline__ float bf2f(ushort u) {
    union { float f; unsigned int i; } c; c.i = ((unsigned int)u) << 16; return c.f;
}
__device__ __forceinline__ ushort f2bf(float f) {
    union { float f; unsigned int i; } c; c.f = f;
    unsigned int x = c.i;
    return (ushort)((x + 0x7FFFu + ((x >> 16) & 1u)) >> 16);  // RNE
}

// async 16B global->LDS (m97; LDS dest must be wave-uniform base + lane*16)
__device__ __forceinline__ void gload_lds16(const ushort* g, ushort* l) {
    __builtin_amdgcn_global_load_lds(
        (const __attribute__((address_space(1))) unsigned int*)g,
        (__attribute__((address_space(3))) unsigned int*)l, 16, 0, 0);
}

// ---------------------------------------------------------------------------
// Prep kernel: LN row-per-wave (blocks 0..2047, 4 rows/block, no barriers)
// + w_qkv transpose tiles (2048..5119) + w_out transpose (5120..6143).
// ---------------------------------------------------------------------------
__global__ __launch_bounds__(256) void prep_kernel(
    const float* __restrict__ x, const float* __restrict__ g,
    const float* __restrict__ b, ushort* __restrict__ xn,
    const float* __restrict__ w_qkv, ushort* __restrict__ wqkvT,
    const float* __restrict__ w_out, ushort* __restrict__ woutT) {
    __shared__ ushort t[32][33];
    int bid = blockIdx.x;
    int tid = threadIdx.x;
    if (bid < 2048) {
        // ---- LayerNorm: one row per wave ----
        int w = tid >> 6, lane = tid & 63;
        int row = bid * 4 + w;
        const float* xr = x + (size_t)row * 1024;
        float v[4][4];
        float s1 = 0.f, s2 = 0.f;
#pragma unroll
        for (int j = 0; j < 4; j++) {
            float4 t4 = *(const float4*)(xr + lane * 4 + j * 256);
            v[j][0] = t4.x; v[j][1] = t4.y; v[j][2] = t4.z; v[j][3] = t4.w;
#pragma unroll
            for (int e = 0; e < 4; e++) { s1 += v[j][e]; s2 += v[j][e] * v[j][e]; }
        }
#pragma unroll
        for (int m = 32; m >= 1; m >>= 1) { s1 += __shfl_xor(s1, m); s2 += __shfl_xor(s2, m); }
        float mu = s1 * (1.0f / 1024.0f);
        float var = s2 * (1.0f / 1024.0f) - mu * mu;
        float rs = rsqrtf(var + 1e-5f);
#pragma unroll
        for (int j = 0; j < 4; j++) {
            int c0 = lane * 4 + j * 256;
            float4 gg = *(const float4*)(g + c0);
            float4 bb = *(const float4*)(b + c0);
            float gA[4] = {gg.x, gg.y, gg.z, gg.w};
            float bA[4] = {bb.x, bb.y, bb.z, bb.w};
            ushort o[4];
#pragma unroll
            for (int e = 0; e < 4; e++) o[e] = f2bf((v[j][e] - mu) * rs * gA[e] + bA[e]);
            uint2 pk;
            pk.x = (uint)o[0] | ((uint)o[1] << 16);
            pk.y = (uint)o[2] | ((uint)o[3] << 16);
            *(uint2*)(xn + (size_t)row * 1024 + c0) = pk;
        }
    } else {
        // ---- weight transpose tile ----
        const float* in; ushort* out; int R, Cc, bx, by;
        if (bid < 5120) {
            int tt = bid - 2048;
            in = w_qkv; out = wqkvT; R = 1024; Cc = 3072;
            bx = (tt % 96) * 32; by = (tt / 96) * 32;
        } else {
            int tt = bid - 5120;
            in = w_out; out = woutT; R = 1024; Cc = 1024;
            bx = (tt % 32) * 32; by = (tt / 32) * 32;
        }
        int tx = tid & 31, ty = tid >> 5;
#pragma unroll
        for (int j = 0; j < 32; j += 8)
            t[ty + j][tx] = f2bf(in[(size_t)(by + ty + j) * Cc + bx + tx]);
        __syncthreads();
#pragma unroll
        for (int j = 0; j < 32; j += 8)
            out[(size_t)(bx + ty + j) * R + by + tx] = t[tx][ty + j];
    }
}

// ---------------------------------------------------------------------------
// Per-head bf16 transpose: in [64][1024][128] -> out [64][128][1024]
// ---------------------------------------------------------------------------
__global__ __launch_bounds__(256) void transpose_head(
    const ushort* __restrict__ in, ushort* __restrict__ out) {
    __shared__ ushort t[32][33];
    int h = blockIdx.z;
    int j0 = blockIdx.y * 32;  // seq pos
    int d0 = blockIdx.x * 32;  // head dim
    int tx = threadIdx.x & 31, ty = threadIdx.x >> 5;
    const ushort* src = in + (size_t)h * 131072;
    ushort* dst = out + (size_t)h * 131072;
#pragma unroll
    for (int j = 0; j < 32; j += 8)
        t[ty + j][tx] = src[(size_t)(j0 + ty + j) * 128 + d0 + tx];
    __syncthreads();
#pragma unroll
    for (int j = 0; j < 32; j += 8)
        dst[(size_t)(d0 + ty + j) * 1024 + j0 + tx] = t[tx][ty + j];
}

// ---------------------------------------------------------------------------
// QKV GEMM R14: C[8192,3072] = A[8192,1024] @ Bt[3072,1024]^T.
// 256x128 tile, BK=64, 512 thr = 8 waves (4M x 2N, 64x64 per wave).
// LDS 96 KB: As[2][256x64] + Bs[2][128x64], double-buffered.
// Pipeline (2-deep, counted vmcnt -- T4):
//   prologue: stage K0->buf0, K1->buf1; vmcnt(6); barrier
//   iter t:   read 16 frags from buf[t&1]; MFMA kk0 (setprio);
//             lgkmcnt(0); barrier            <- buf[t&1] now free (all waves)
//             stage K(t+2)->buf[t&1];        <- 6 gloads, ~1.5 iters to land
//             MFMA kk1 (setprio);
//             vmcnt(6); barrier              <- K(t+1) landed, K(t+2) in flight
// Never drains vmcnt to 0 in steady state.  XOR-8 chunk swizzle (proven
// conflict-free).  Grid 768 = 3 exact CU waves.
// R14 swizzle: XCD x owns M-tiles [4x,4x+4) (A band 2MB stays L2-resident),
// N-fastest within the band.  A fetched once globally, B once per XCD.
// ---------------------------------------------------------------------------
__device__ __forceinline__ void stage6(const ushort* __restrict__ Ab,
                                       const ushort* __restrict__ Bb, int t2,
                                       ushort* AsD, ushort* BsD, int tid) {
    const ushort* As_src = Ab + t2 * 64;
    const ushort* Bs_src = Bb + t2 * 64;
#pragma unroll
    for (int i = 0; i < 4; i++) {
        int lin = i * 512 + tid;             // 0..2047: 16B chunk id of A tile
        int r = lin >> 3, p = lin & 7;
        int l = p ^ (r & 7);                 // logical chunk at phys slot p
        gload_lds16(As_src + (size_t)r * 1024 + l * 8, &AsD[lin * 8]);
    }
#pragma unroll
    for (int i = 0; i < 2; i++) {
        int lin = i * 512 + tid;             // 0..1023: chunk id of B tile
        int r = lin >> 3, p = lin & 7;
        int l = p ^ (r & 7);
        gload_lds16(Bs_src + (size_t)r * 1024 + l * 8, &BsD[lin * 8]);
    }
}

__global__ __launch_bounds__(512, 2) void gemm_qkv(
    const ushort* __restrict__ A, const ushort* __restrict__ Bt,
    const float* __restrict__ bias, ushort* __restrict__ out0,
    ushort* __restrict__ out1, ushort* __restrict__ out2) {
    __shared__ __align__(16) ushort As[2][256 * 64];  // 64 KB
    __shared__ __align__(16) ushort Bs[2][128 * 64];  // 32 KB

    int tid = threadIdx.x;
    int lane = tid & 63, w = tid >> 6;       // 8 waves
    int l15 = lane & 15, q4 = lane >> 4;
    int wrM = (w >> 1) * 64;                 // wave M offset: 0/64/128/192
    int wcN = (w & 1) * 64;                  // wave N offset: 0/64

    // R14 XCD swizzle: dispatch round-robins XCDs on bid&7.  XCD x owns
    // M-tiles 4x..4x+3 (A working set 4x512KB=2MB, resident in its 4MB L2
    // for the whole kernel); within the band, N-fastest after M-group of 4.
    // Bijective: by -> (xcd=by>>2, i&3=by&3), bx -> i>>2.
    int bid = blockIdx.x;
    int xcd = bid & 7;
    int i = bid >> 3;                        // 0..95
    int by = xcd * 4 + (i & 3);              // M-tile 0..31
    int bx = i >> 2;                         // N-tile 0..23
    int rowBase = by * 256, colBase = bx * 128;

    const ushort* Ab = A + (size_t)rowBase * 1024;
    const ushort* Bb = Bt + (size_t)colBase * 1024;

    f32x4 acc[4][4];
    f32x4 zero = {0.f, 0.f, 0.f, 0.f};
#pragma unroll
    for (int mi = 0; mi < 4; mi++)
#pragma unroll
        for (int ni = 0; ni < 4; ni++) acc[mi][ni] = zero;

    // prologue: fill both buffers, wait only for buf0 (K1 stays in flight)
    stage6(Ab, Bb, 0, &As[0][0], &Bs[0][0], tid);
    stage6(Ab, Bb, 1, &As[1][0], &Bs[1][0], tid);
    asm volatile("s_waitcnt vmcnt(6)" ::: "memory");
    __builtin_amdgcn_s_barrier();

    for (int t = 0; t < 16; ++t) {
        const int cur = t & 1;
        const ushort* Ac = &As[cur][0];
        const ushort* Bc = &Bs[cur][0];

        // ---- read all 16 fragments of this K-tile into registers ----
        short8 aF[4][2], bF[4][2];
#pragma unroll
        for (int kk = 0; kk < 2; kk++) {
#pragma unroll
            for (int mi = 0; mi < 4; mi++) {
                int r = wrM + mi * 16 + l15;
                aF[mi][kk] = *(const short8*)&Ac[r * 64 + ((kk * 4 + q4) ^ (r & 7)) * 8];
            }
#pragma unroll
            for (int ni = 0; ni < 4; ni++) {
                int r = wcN + ni * 16 + l15;
                bF[ni][kk] = *(const short8*)&Bc[r * 64 + ((kk * 4 + q4) ^ (r & 7)) * 8];
            }
        }

        // ---- MFMA kk=0 (compiler inserts partial lgkmcnt; kk1 reads fly) ----
        __builtin_amdgcn_s_setprio(1);
#pragma unroll
        for (int mi = 0; mi < 4; mi++)
#pragma unroll
            for (int ni = 0; ni < 4; ni++)
                acc[mi][ni] = __builtin_amdgcn_mfma_f32_16x16x32_bf16(
                    aF[mi][0], bF[ni][0], acc[mi][ni], 0, 0, 0);
        __builtin_amdgcn_s_setprio(0);

        // all 16 reads sampled -> buf[cur] free for restaging (block-wide)
        asm volatile("s_waitcnt lgkmcnt(0)" ::: "memory");
        __builtin_amdgcn_s_barrier();
        if (t < 14) stage6(Ab, Bb, t + 2, &As[cur][0], &Bs[cur][0], tid);

        // ---- MFMA kk=1 (hides the stage issue + in-flight loads) ----
        __builtin_amdgcn_s_setprio(1);
#pragma unroll
        for (int mi = 0; mi < 4; mi++)
#pragma unroll
            for (int ni = 0; ni < 4; ni++)
                acc[mi][ni] = __builtin_amdgcn_mfma_f32_16x16x32_bf16(
                    aF[mi][1], bF[ni][1], acc[mi][ni], 0, 0, 0);
        __builtin_amdgcn_s_setprio(0);

        if (t < 15) {
            if (t < 14) asm volatile("s_waitcnt vmcnt(6)" ::: "memory");
            else        asm volatile("s_waitcnt vmcnt(0)" ::: "memory");
            __builtin_amdgcn_s_barrier();
        }
    }

    // C layout: col = lane&15, row = (lane>>4)*4 + r  [m89/m91]
#pragma unroll
    for (int ni = 0; ni < 4; ni++) {
        int col = colBase + wcN + ni * 16 + l15;
        float bv = bias[col];
        float sc = (col < 2048) ? QK_SCALE : 1.0f;
        int bsel = col >> 10, cc = col & 1023;
        ushort* dst = (bsel == 0) ? out0 : ((bsel == 1) ? out1 : out2);
#pragma unroll
        for (int mi = 0; mi < 4; mi++) {
            f32x4 a = acc[mi][ni];
#pragma unroll
            for (int r = 0; r < 4; r++) {
                int row = rowBase + wrM + mi * 16 + q4 * 4 + r;
                dst[(size_t)row * 1024 + cc] = f2bf((a[r] + bv) * sc);
            }
        }
    }
}

// ---------------------------------------------------------------------------
// Out-proj GEMM: outf[M,1024] = A[M,1024] @ Bt[1024,1024]^T + bias + resid.
// 64x128 tile, BK=64, XOR-8 swizzle, grid (8,128)=1024 blocks, 24 KB LDS.
// (256,4) measured spill-free.
// ---------------------------------------------------------------------------
__global__ __launch_bounds__(256, 4) void gemm_out(
    const ushort* __restrict__ A, const ushort* __restrict__ Bt,
    const float* __restrict__ bias, const ushort* __restrict__ resid,
    float* __restrict__ outf) {
    const int K = 1024;
    __shared__ __align__(16) ushort As[64 * 64];    //  8 KB, 512 chunks
    __shared__ __align__(16) ushort Bs[128 * 64];   // 16 KB, 1024 chunks

    int tid = threadIdx.x;
    int lane = tid & 63, w = tid >> 6;
    int l15 = lane & 15, q4 = lane >> 4;
    int wr = (w >> 1) * 32, wc = (w & 1) * 64;
    int rowBase = blockIdx.y * 64, colBase = blockIdx.x * 128;

    const ushort* src[6]; ushort* dstp[6];
#pragma unroll
    for (int i = 0; i < 6; i++) {
        int id = i * 256 + w * 64 + lane;  // 0..1535
        if (id < 512) {
            int r = id >> 3, l = (id & 7) ^ ((id >> 3) & 7);
            src[i] = A + (size_t)(rowBase + r) * K + l * 8;
            dstp[i] = &As[id * 8];
        } else {
            int idb = id - 512;
            int r = idb >> 3, l = (idb & 7) ^ ((idb >> 3) & 7);
            src[i] = Bt + (size_t)(colBase + r) * K + l * 8;
            dstp[i] = &Bs[idb * 8];
        }
    }

    f32x4 acc[2][4];
    f32x4 zero = {0.f, 0.f, 0.f, 0.f};
#pragma unroll
    for (int mi = 0; mi < 2; mi++)
#pragma unroll
        for (int ni = 0; ni < 4; ni++) acc[mi][ni] = zero;

    for (int kt = 0; kt < 16; kt++) {
        __syncthreads();
#pragma unroll
        for (int i = 0; i < 6; i++) {
            gload_lds16(src[i], dstp[i]);
            src[i] += 64;
        }
        __syncthreads();

#pragma unroll
        for (int kk = 0; kk < 2; kk++) {
            short8 aF[2], bF[4];
#pragma unroll
            for (int mi = 0; mi < 2; mi++) {
                int r = wr + mi * 16 + l15;
                aF[mi] = *(const short8*)&As[r * 64 + ((kk * 4 + q4) ^ (r & 7)) * 8];
            }
#pragma unroll
            for (int ni = 0; ni < 4; ni++) {
                int r = wc + ni * 16 + l15;
                bF[ni] = *(const short8*)&Bs[r * 64 + ((kk * 4 + q4) ^ (r & 7)) * 8];
            }
#pragma unroll
            for (int mi = 0; mi < 2; mi++)
#pragma unroll
                for (int ni = 0; ni < 4; ni++)
                    acc[mi][ni] = __builtin_amdgcn_mfma_f32_16x16x32_bf16(
                        aF[mi], bF[ni], acc[mi][ni], 0, 0, 0);
        }
    }

#pragma unroll
    for (int ni = 0; ni < 4; ni++) {
        int col = colBase + wc + ni * 16 + l15;
        float bv = bias[col];
#pragma unroll
        for (int mi = 0; mi < 2; mi++) {
            f32x4 a = acc[mi][ni];
#pragma unroll
            for (int r = 0; r < 4; r++) {
                int row = rowBase + wr + mi * 16 + q4 * 4 + r;
                outf[(size_t)row * 1024 + col] =
                    a[r] + bv + bf2f(resid[(size_t)row * 1024 + col]);
            }
        }
    }
}

// ---------------------------------------------------------------------------
// Attention v7: one block = (head g, 128 q-rows); 8 waves x 16q; 512 thr.
// One K/V staging serves 2x the compute of v4: per-thread staging gloads
// halve (8->4/kt) and per-head K/V re-staging halves (8 q-blocks vs 16).
// LDS 48 KB (Ks 16K + Vt 16K + Ps 16K).  Per-wave math identical to v4.
//  - Ks [64 key][128 d], XOR-16 chunk swizzle, global_load_lds staged
//  - Vt [128 d][64 key], XOR-8 chunk swizzle, global_load_lds staged
//  - Ps [128 q][64 key], XOR-8 chunk swizzle, wave-private rows
// ---------------------------------------------------------------------------
__global__ __launch_bounds__(512) void attn_kernel(
    const ushort* __restrict__ qb, const ushort* __restrict__ kb,
    const ushort* __restrict__ vt, ushort* __restrict__ ob) {
    int g = blockIdx.x >> 3;       // head 0..63
    int qblk = blockIdx.x & 7;     // 128-row q block
    const ushort* Qh = qb + (size_t)g * 131072;
    const ushort* Kh = kb + (size_t)g * 131072;
    const ushort* Vh = vt + (size_t)g * 131072;  // [128 d][1024 key]

    __shared__ __align__(16) ushort Ks[64 * 128];   // 16 KB
    __shared__ __align__(16) ushort Vt[128 * 64];   // 16 KB
    __shared__ __align__(16) ushort Ps[128 * 64];   // 16 KB

    int tid = threadIdx.x, lane = tid & 63, w = tid >> 6;  // w in [0,8)
    int l15 = lane & 15, q4 = lane >> 4;
    int q0 = qblk * 128;

    // Q A-fragments: A[m=l15][k = ks*32 + q4*8 + j]
    short8 qf[4];
#pragma unroll
    for (int ks = 0; ks < 4; ks++)
        qf[ks] = *(const short8*)&Qh[(size_t)(q0 + w * 16 + l15) * 128 + ks * 32 + q4 * 8];

    f32x4 zero = {0.f, 0.f, 0.f, 0.f};
    f32x4 o[8];
#pragma unroll
    for (int ni = 0; ni < 8; ni++) o[ni] = zero;
    float plsum[4] = {0.f, 0.f, 0.f, 0.f};

    for (int kt = 0; kt < 16; kt++) {
        __syncthreads();
        // Ks: phys chunk p in key-row r holds logical chunk l = p ^ (r&15)
#pragma unroll
        for (int i = 0; i < 2; i++) {
            int linear = i * 512 + tid;          // 0..1023, wave-contiguous
            int r = linear >> 4, p = linear & 15;
            int l = p ^ (r & 15);
            gload_lds16(&Kh[(size_t)(kt * 64 + r) * 128 + l * 8], &Ks[linear * 8]);
        }
        // Vt: phys chunk p in d-row holds logical chunk c = p ^ (d&7)
#pragma unroll
        for (int i = 0; i < 2; i++) {
            int linear = i * 512 + tid;          // 0..1023
            int d = linear >> 3, p = linear & 7;
            int c = p ^ (d & 7);
            gload_lds16(&Vh[(size_t)d * 1024 + kt * 64 + c * 8], &Vt[linear * 8]);
        }
        __syncthreads();

        // S = Q K^T : 16q x 64key per wave
        f32x4 sacc[4];
#pragma unroll
        for (int ni = 0; ni < 4; ni++) sacc[ni] = zero;
#pragma unroll
        for (int ks = 0; ks < 4; ks++) {
#pragma unroll
            for (int ni = 0; ni < 4; ni++) {
                int r = ni * 16 + l15;
                int p = (ks * 4 + q4) ^ (r & 15);
                short8 bF = *(const short8*)&Ks[r * 128 + p * 8];
                sacc[ni] = __builtin_amdgcn_mfma_f32_16x16x32_bf16(
                    qf[ks], bF, sacc[ni], 0, 0, 0);
            }
        }

        // P = exp(S) -> Ps (swizzled); accumulate per-lane partial row sums
#pragma unroll
        for (int ni = 0; ni < 4; ni++) {
#pragma unroll
            for (int r = 0; r < 4; r++) {
                float pv = __expf(sacc[ni][r]);
                plsum[r] += pv;
                int qloc = w * 16 + q4 * 4 + r;       // wave-private rows
                int key = ni * 16 + l15;
                int pc = (key >> 3) ^ (qloc & 7);
                Ps[qloc * 64 + pc * 8 + (key & 7)] = f2bf(pv);
            }
        }

        // O += P V  (wave-private Ps rows; same-wave RAW handled by waitcnt)
#pragma unroll
        for (int ks2 = 0; ks2 < 2; ks2++) {
            int c = ks2 * 4 + q4;
            int row = w * 16 + l15;                   // row&7 == l15&7
            short8 aF = *(const short8*)&Ps[row * 64 + (c ^ (l15 & 7)) * 8];
#pragma unroll
            for (int ni = 0; ni < 8; ni++) {
                int d = ni * 16 + l15;
                short8 bF = *(const short8*)&Vt[d * 64 + (c ^ (d & 7)) * 8];
                o[ni] = __builtin_amdgcn_mfma_f32_16x16x32_bf16(aF, bF, o[ni], 0, 0, 0);
            }
        }
    }

    // row sums: reduce per-lane partials over the 16 l15-lanes
#pragma unroll
    for (int r = 0; r < 4; r++) {
#pragma unroll
        for (int m = 1; m < 16; m <<= 1) plsum[r] += __shfl_xor(plsum[r], m, 16);
    }
    float inv[4];
#pragma unroll
    for (int r = 0; r < 4; r++) inv[r] = 1.0f / plsum[r];
#pragma unroll
    for (int ni = 0; ni < 8; ni++)
#pragma unroll
        for (int r = 0; r < 4; r++) {
            int qrow = q0 + w * 16 + q4 * 4 + r;
            ob[(size_t)g * 131072 + (size_t)qrow * 128 + ni * 16 + l15] =
                f2bf(o[ni][r] * inv[r]);
        }
}

// ---------------------------------------------------------------------------
extern "C" void kernel_launch(void* const* d_in, const int* in_sizes, int n_in,
                              void* d_out, int out_size, void* d_ws, size_t ws_size,
                              hipStream_t stream) {
    const float* x     = (const float*)d_in[0];
    const float* ln_g  = (const float*)d_in[1];
    const float* ln_b  = (const float*)d_in[2];
    const float* w_qkv = (const float*)d_in[3];
    const float* b_qkv = (const float*)d_in[4];
    const float* w_out = (const float*)d_in[5];
    const float* b_out = (const float*)d_in[6];
    float* out = (float*)d_out;

    const size_t MC = 8192ull * 1024ull;  // 8.39M elems
    ushort* xn    = (ushort*)d_ws;
    ushort* wqkvT = xn + MC;
    ushort* woutT = wqkvT + 3072ull * 1024ull;
    ushort* qbuf  = woutT + 1024ull * 1024ull;
    ushort* kbuf  = qbuf + MC;
    ushort* vtbuf = kbuf + MC;        // V^T [64 heads][128 d][1024 seq]
    ushort* attnb = vtbuf + MC;       // scratch for raw V, then attn output
    // total: 46.14M ushorts = 92.3 MB (same layout as passing rounds 2-10)

    prep_kernel<<<6144, 256, 0, stream>>>(x, ln_g, ln_b, xn, w_qkv, wqkvT, w_out, woutT);
    // q,k -> qbuf,kbuf ; v -> attnb (scratch, row-major coalesced)
    gemm_qkv<<<768, 512, 0, stream>>>(xn, wqkvT, b_qkv, qbuf, kbuf, attnb);
    transpose_head<<<dim3(4, 32, 64), 256, 0, stream>>>(attnb, vtbuf);
    attn_kernel<<<512, 512, 0, stream>>>(qbuf, kbuf, vtbuf, attnb);
    gemm_out<<<dim3(8, 128), 256, 0, stream>>>(attnb, woutT, b_out, xn, out);
}

// Round 4
// 243.809 us; speedup vs baseline: 1.0938x; 1.0232x over previous
//
#include <hip/hip_runtime.h>
#include <hip/hip_bf16.h>

// ---------------------------------------------------------------------------
// AttentionBlock: B=8, L=1024, C=1024, H=8, ch=128.
// fp32 I/O, bf16 MFMA internal.  Head split is a free flat reinterpret.
// R8 lesson: scattered 2B global stores amplify HBM writes ~10x.
// R9 lesson: launch_bounds floors past VGPR need -> scratch spills (1 GB HBM).
// R11: attn blocks widened to 512 thr / 8 waves sharing one K/V staging.
// R12: gemm_qkv 2-deep counted-vmcnt pipeline (T3/T4/T5).
// R13 lesson (measured): M-fast XCD swizzle -> 200MB fetch, 83.5us.
// R14 lesson (measured): XCD M-band swizzle -> 49MB fetch, 61.5us, but
//      MfmaUtil still 31%: LDS 96KB = 1 block/CU, all 8 waves in ONE
//      barrier group -> lockstep ds_read burst / MFMA burst, no overlap.
// R15: 128x128 tile, 256 thr, 64KB LDS -> 2 blocks/CU.  Two independent
//      barrier groups desynchronize: one block's MFMA fills the other's
//      barrier/ds_read gaps (m114).  Pipeline discipline unchanged.
// ---------------------------------------------------------------------------

typedef __attribute__((ext_vector_type(8))) short short8;
typedef __attribute__((ext_vector_type(4))) float f32x4;

#define QK_SCALE 0.29730177875068026f  // 128^-0.25

__device__ __forceinline__ float bf2f(ushort u) {
    union { float f; unsigned int i; } c; c.i = ((unsigned int)u) << 16; return c.f;
}
__device__ __forceinline__ ushort f2bf(float f) {
    union { float f; unsigned int i; } c; c.f = f;
    unsigned int x = c.i;
    return (ushort)((x + 0x7FFFu + ((x >> 16) & 1u)) >> 16);  // RNE
}

// async 16B global->LDS (m97; LDS dest must be wave-uniform base + lane*16)
__device__ __forceinline__ void gload_lds16(const ushort* g, ushort* l) {
    __builtin_amdgcn_global_load_lds(
        (const __attribute__((address_space(1))) unsigned int*)g,
        (__attribute__((address_space(3))) unsigned int*)l, 16, 0, 0);
}

// ---------------------------------------------------------------------------
// Prep kernel: LN row-per-wave (blocks 0..2047, 4 rows/block, no barriers)
// + w_qkv transpose tiles (2048..5119) + w_out transpose (5120..6143).
// ---------------------------------------------------------------------------
__global__ __launch_bounds__(256) void prep_kernel(
    const float* __restrict__ x, const float* __restrict__ g,
    const float* __restrict__ b, ushort* __restrict__ xn,
    const float* __restrict__ w_qkv, ushort* __restrict__ wqkvT,
    const float* __restrict__ w_out, ushort* __restrict__ woutT) {
    __shared__ ushort t[32][33];
    int bid = blockIdx.x;
    int tid = threadIdx.x;
    if (bid < 2048) {
        // ---- LayerNorm: one row per wave ----
        int w = tid >> 6, lane = tid & 63;
        int row = bid * 4 + w;
        const float* xr = x + (size_t)row * 1024;
        float v[4][4];
        float s1 = 0.f, s2 = 0.f;
#pragma unroll
        for (int j = 0; j < 4; j++) {
            float4 t4 = *(const float4*)(xr + lane * 4 + j * 256);
            v[j][0] = t4.x; v[j][1] = t4.y; v[j][2] = t4.z; v[j][3] = t4.w;
#pragma unroll
            for (int e = 0; e < 4; e++) { s1 += v[j][e]; s2 += v[j][e] * v[j][e]; }
        }
#pragma unroll
        for (int m = 32; m >= 1; m >>= 1) { s1 += __shfl_xor(s1, m); s2 += __shfl_xor(s2, m); }
        float mu = s1 * (1.0f / 1024.0f);
        float var = s2 * (1.0f / 1024.0f) - mu * mu;
        float rs = rsqrtf(var + 1e-5f);
#pragma unroll
        for (int j = 0; j < 4; j++) {
            int c0 = lane * 4 + j * 256;
            float4 gg = *(const float4*)(g + c0);
            float4 bb = *(const float4*)(b + c0);
            float gA[4] = {gg.x, gg.y, gg.z, gg.w};
            float bA[4] = {bb.x, bb.y, bb.z, bb.w};
            ushort o[4];
#pragma unroll
            for (int e = 0; e < 4; e++) o[e] = f2bf((v[j][e] - mu) * rs * gA[e] + bA[e]);
            uint2 pk;
            pk.x = (uint)o[0] | ((uint)o[1] << 16);
            pk.y = (uint)o[2] | ((uint)o[3] << 16);
            *(uint2*)(xn + (size_t)row * 1024 + c0) = pk;
        }
    } else {
        // ---- weight transpose tile ----
        const float* in; ushort* out; int R, Cc, bx, by;
        if (bid < 5120) {
            int tt = bid - 2048;
            in = w_qkv; out = wqkvT; R = 1024; Cc = 3072;
            bx = (tt % 96) * 32; by = (tt / 96) * 32;
        } else {
            int tt = bid - 5120;
            in = w_out; out = woutT; R = 1024; Cc = 1024;
            bx = (tt % 32) * 32; by = (tt / 32) * 32;
        }
        int tx = tid & 31, ty = tid >> 5;
#pragma unroll
        for (int j = 0; j < 32; j += 8)
            t[ty + j][tx] = f2bf(in[(size_t)(by + ty + j) * Cc + bx + tx]);
        __syncthreads();
#pragma unroll
        for (int j = 0; j < 32; j += 8)
            out[(size_t)(bx + ty + j) * R + by + tx] = t[tx][ty + j];
    }
}

// ---------------------------------------------------------------------------
// Per-head bf16 transpose: in [64][1024][128] -> out [64][128][1024]
// ---------------------------------------------------------------------------
__global__ __launch_bounds__(256) void transpose_head(
    const ushort* __restrict__ in, ushort* __restrict__ out) {
    __shared__ ushort t[32][33];
    int h = blockIdx.z;
    int j0 = blockIdx.y * 32;  // seq pos
    int d0 = blockIdx.x * 32;  // head dim
    int tx = threadIdx.x & 31, ty = threadIdx.x >> 5;
    const ushort* src = in + (size_t)h * 131072;
    ushort* dst = out + (size_t)h * 131072;
#pragma unroll
    for (int j = 0; j < 32; j += 8)
        t[ty + j][tx] = src[(size_t)(j0 + ty + j) * 128 + d0 + tx];
    __syncthreads();
#pragma unroll
    for (int j = 0; j < 32; j += 8)
        dst[(size_t)(d0 + ty + j) * 1024 + j0 + tx] = t[tx][ty + j];
}

// ---------------------------------------------------------------------------
// QKV GEMM R15: C[8192,3072] = A[8192,1024] @ Bt[3072,1024]^T.
// 128x128 tile, BK=64, 256 thr = 4 waves (2M x 2N, 64x64 per wave).
// LDS 64 KB: As[2][128x64] + Bs[2][128x64] -> 2 blocks/CU (desync overlap).
// Pipeline (2-deep, counted vmcnt -- T4), 8 gloads per stage:
//   prologue: stage K0->buf0, K1->buf1; vmcnt(8); barrier
//   iter t:   read 16 frags from buf[t&1]; MFMA kk0 (setprio);
//             lgkmcnt(0); barrier            <- buf[t&1] free (all waves)
//             stage K(t+2)->buf[t&1];        <- outstanding 16
//             MFMA kk1 (setprio);
//             vmcnt(8); barrier              <- K(t+1) landed
// XOR-8 chunk swizzle (proven conflict-free).  Grid 1536 = 2/CU x 3 waves.
// XCD x owns M-tiles [8x,8x+8) (2MB A band, L2-resident), N-fastest.
// ---------------------------------------------------------------------------
__device__ __forceinline__ void stage8(const ushort* __restrict__ Ab,
                                       const ushort* __restrict__ Bb, int t2,
                                       ushort* AsD, ushort* BsD, int tid) {
    const ushort* As_src = Ab + t2 * 64;
    const ushort* Bs_src = Bb + t2 * 64;
#pragma unroll
    for (int i = 0; i < 4; i++) {
        int lin = i * 256 + tid;             // 0..1023: 16B chunk id of A tile
        int r = lin >> 3, p = lin & 7;
        int l = p ^ (r & 7);                 // logical chunk at phys slot p
        gload_lds16(As_src + (size_t)r * 1024 + l * 8, &AsD[lin * 8]);
    }
#pragma unroll
    for (int i = 0; i < 4; i++) {
        int lin = i * 256 + tid;             // 0..1023: chunk id of B tile
        int r = lin >> 3, p = lin & 7;
        int l = p ^ (r & 7);
        gload_lds16(Bs_src + (size_t)r * 1024 + l * 8, &BsD[lin * 8]);
    }
}

__global__ __launch_bounds__(256, 2) void gemm_qkv(
    const ushort* __restrict__ A, const ushort* __restrict__ Bt,
    const float* __restrict__ bias, ushort* __restrict__ out0,
    ushort* __restrict__ out1, ushort* __restrict__ out2) {
    __shared__ __align__(16) ushort As[2][128 * 64];  // 32 KB
    __shared__ __align__(16) ushort Bs[2][128 * 64];  // 32 KB

    int tid = threadIdx.x;
    int lane = tid & 63, w = tid >> 6;       // 4 waves
    int l15 = lane & 15, q4 = lane >> 4;
    int wrM = (w >> 1) * 64;                 // wave M offset: 0/64
    int wcN = (w & 1) * 64;                  // wave N offset: 0/64

    // R15 XCD swizzle: XCD x owns M-tiles 8x..8x+7 (A band 2MB, L2-resident
    // for the whole kernel); N-fastest within the band.
    int bid = blockIdx.x;
    int xcd = bid & 7;
    int i = bid >> 3;                        // 0..191
    int by = xcd * 8 + (i & 7);              // M-tile 0..63
    int bx = i >> 3;                         // N-tile 0..23
    int rowBase = by * 128, colBase = bx * 128;

    const ushort* Ab = A + (size_t)rowBase * 1024;
    const ushort* Bb = Bt + (size_t)colBase * 1024;

    f32x4 acc[4][4];
    f32x4 zero = {0.f, 0.f, 0.f, 0.f};
#pragma unroll
    for (int mi = 0; mi < 4; mi++)
#pragma unroll
        for (int ni = 0; ni < 4; ni++) acc[mi][ni] = zero;

    // prologue: fill both buffers, wait only for buf0 (K1 stays in flight)
    stage8(Ab, Bb, 0, &As[0][0], &Bs[0][0], tid);
    stage8(Ab, Bb, 1, &As[1][0], &Bs[1][0], tid);
    asm volatile("s_waitcnt vmcnt(8)" ::: "memory");
    __builtin_amdgcn_s_barrier();

    for (int t = 0; t < 16; ++t) {
        const int cur = t & 1;
        const ushort* Ac = &As[cur][0];
        const ushort* Bc = &Bs[cur][0];

        // ---- read all 16 fragments of this K-tile into registers ----
        short8 aF[4][2], bF[4][2];
#pragma unroll
        for (int kk = 0; kk < 2; kk++) {
#pragma unroll
            for (int mi = 0; mi < 4; mi++) {
                int r = wrM + mi * 16 + l15;
                aF[mi][kk] = *(const short8*)&Ac[r * 64 + ((kk * 4 + q4) ^ (r & 7)) * 8];
            }
#pragma unroll
            for (int ni = 0; ni < 4; ni++) {
                int r = wcN + ni * 16 + l15;
                bF[ni][kk] = *(const short8*)&Bc[r * 64 + ((kk * 4 + q4) ^ (r & 7)) * 8];
            }
        }

        // ---- MFMA kk=0 (compiler inserts partial lgkmcnt; kk1 reads fly) ----
        __builtin_amdgcn_s_setprio(1);
#pragma unroll
        for (int mi = 0; mi < 4; mi++)
#pragma unroll
            for (int ni = 0; ni < 4; ni++)
                acc[mi][ni] = __builtin_amdgcn_mfma_f32_16x16x32_bf16(
                    aF[mi][0], bF[ni][0], acc[mi][ni], 0, 0, 0);
        __builtin_amdgcn_s_setprio(0);

        // all 16 reads sampled -> buf[cur] free for restaging (block-wide)
        asm volatile("s_waitcnt lgkmcnt(0)" ::: "memory");
        __builtin_amdgcn_s_barrier();
        if (t < 14) stage8(Ab, Bb, t + 2, &As[cur][0], &Bs[cur][0], tid);

        // ---- MFMA kk=1 (hides the stage issue + in-flight loads) ----
        __builtin_amdgcn_s_setprio(1);
#pragma unroll
        for (int mi = 0; mi < 4; mi++)
#pragma unroll
            for (int ni = 0; ni < 4; ni++)
                acc[mi][ni] = __builtin_amdgcn_mfma_f32_16x16x32_bf16(
                    aF[mi][1], bF[ni][1], acc[mi][ni], 0, 0, 0);
        __builtin_amdgcn_s_setprio(0);

        if (t < 15) {
            if (t < 14) asm volatile("s_waitcnt vmcnt(8)" ::: "memory");
            else        asm volatile("s_waitcnt vmcnt(0)" ::: "memory");
            __builtin_amdgcn_s_barrier();
        }
    }

    // C layout: col = lane&15, row = (lane>>4)*4 + r  [m89/m91]
#pragma unroll
    for (int ni = 0; ni < 4; ni++) {
        int col = colBase + wcN + ni * 16 + l15;
        float bv = bias[col];
        float sc = (col < 2048) ? QK_SCALE : 1.0f;
        int bsel = col >> 10, cc = col & 1023;
        ushort* dst = (bsel == 0) ? out0 : ((bsel == 1) ? out1 : out2);
#pragma unroll
        for (int mi = 0; mi < 4; mi++) {
            f32x4 a = acc[mi][ni];
#pragma unroll
            for (int r = 0; r < 4; r++) {
                int row = rowBase + wrM + mi * 16 + q4 * 4 + r;
                dst[(size_t)row * 1024 + cc] = f2bf((a[r] + bv) * sc);
            }
        }
    }
}

// ---------------------------------------------------------------------------
// Out-proj GEMM: outf[M,1024] = A[M,1024] @ Bt[1024,1024]^T + bias + resid.
// 64x128 tile, BK=64, XOR-8 swizzle, grid (8,128)=1024 blocks, 24 KB LDS.
// (256,4) measured spill-free.
// ---------------------------------------------------------------------------
__global__ __launch_bounds__(256, 4) void gemm_out(
    const ushort* __restrict__ A, const ushort* __restrict__ Bt,
    const float* __restrict__ bias, const ushort* __restrict__ resid,
    float* __restrict__ outf) {
    const int K = 1024;
    __shared__ __align__(16) ushort As[64 * 64];    //  8 KB, 512 chunks
    __shared__ __align__(16) ushort Bs[128 * 64];   // 16 KB, 1024 chunks

    int tid = threadIdx.x;
    int lane = tid & 63, w = tid >> 6;
    int l15 = lane & 15, q4 = lane >> 4;
    int wr = (w >> 1) * 32, wc = (w & 1) * 64;
    int rowBase = blockIdx.y * 64, colBase = blockIdx.x * 128;

    const ushort* src[6]; ushort* dstp[6];
#pragma unroll
    for (int i = 0; i < 6; i++) {
        int id = i * 256 + w * 64 + lane;  // 0..1535
        if (id < 512) {
            int r = id >> 3, l = (id & 7) ^ ((id >> 3) & 7);
            src[i] = A + (size_t)(rowBase + r) * K + l * 8;
            dstp[i] = &As[id * 8];
        } else {
            int idb = id - 512;
            int r = idb >> 3, l = (idb & 7) ^ ((idb >> 3) & 7);
            src[i] = Bt + (size_t)(colBase + r) * K + l * 8;
            dstp[i] = &Bs[idb * 8];
        }
    }

    f32x4 acc[2][4];
    f32x4 zero = {0.f, 0.f, 0.f, 0.f};
#pragma unroll
    for (int mi = 0; mi < 2; mi++)
#pragma unroll
        for (int ni = 0; ni < 4; ni++) acc[mi][ni] = zero;

    for (int kt = 0; kt < 16; kt++) {
        __syncthreads();
#pragma unroll
        for (int i = 0; i < 6; i++) {
            gload_lds16(src[i], dstp[i]);
            src[i] += 64;
        }
        __syncthreads();

#pragma unroll
        for (int kk = 0; kk < 2; kk++) {
            short8 aF[2], bF[4];
#pragma unroll
            for (int mi = 0; mi < 2; mi++) {
                int r = wr + mi * 16 + l15;
                aF[mi] = *(const short8*)&As[r * 64 + ((kk * 4 + q4) ^ (r & 7)) * 8];
            }
#pragma unroll
            for (int ni = 0; ni < 4; ni++) {
                int r = wc + ni * 16 + l15;
                bF[ni] = *(const short8*)&Bs[r * 64 + ((kk * 4 + q4) ^ (r & 7)) * 8];
            }
#pragma unroll
            for (int mi = 0; mi < 2; mi++)
#pragma unroll
                for (int ni = 0; ni < 4; ni++)
                    acc[mi][ni] = __builtin_amdgcn_mfma_f32_16x16x32_bf16(
                        aF[mi], bF[ni], acc[mi][ni], 0, 0, 0);
        }
    }

#pragma unroll
    for (int ni = 0; ni < 4; ni++) {
        int col = colBase + wc + ni * 16 + l15;
        float bv = bias[col];
#pragma unroll
        for (int mi = 0; mi < 2; mi++) {
            f32x4 a = acc[mi][ni];
#pragma unroll
            for (int r = 0; r < 4; r++) {
                int row = rowBase + wr + mi * 16 + q4 * 4 + r;
                outf[(size_t)row * 1024 + col] =
                    a[r] + bv + bf2f(resid[(size_t)row * 1024 + col]);
            }
        }
    }
}

// ---------------------------------------------------------------------------
// Attention v7: one block = (head g, 128 q-rows); 8 waves x 16q; 512 thr.
// One K/V staging serves 2x the compute of v4: per-thread staging gloads
// halve (8->4/kt) and per-head K/V re-staging halves (8 q-blocks vs 16).
// LDS 48 KB (Ks 16K + Vt 16K + Ps 16K).  Per-wave math identical to v4.
//  - Ks [64 key][128 d], XOR-16 chunk swizzle, global_load_lds staged
//  - Vt [128 d][64 key], XOR-8 chunk swizzle, global_load_lds staged
//  - Ps [128 q][64 key], XOR-8 chunk swizzle, wave-private rows
// ---------------------------------------------------------------------------
__global__ __launch_bounds__(512) void attn_kernel(
    const ushort* __restrict__ qb, const ushort* __restrict__ kb,
    const ushort* __restrict__ vt, ushort* __restrict__ ob) {
    int g = blockIdx.x >> 3;       // head 0..63
    int qblk = blockIdx.x & 7;     // 128-row q block
    const ushort* Qh = qb + (size_t)g * 131072;
    const ushort* Kh = kb + (size_t)g * 131072;
    const ushort* Vh = vt + (size_t)g * 131072;  // [128 d][1024 key]

    __shared__ __align__(16) ushort Ks[64 * 128];   // 16 KB
    __shared__ __align__(16) ushort Vt[128 * 64];   // 16 KB
    __shared__ __align__(16) ushort Ps[128 * 64];   // 16 KB

    int tid = threadIdx.x, lane = tid & 63, w = tid >> 6;  // w in [0,8)
    int l15 = lane & 15, q4 = lane >> 4;
    int q0 = qblk * 128;

    // Q A-fragments: A[m=l15][k = ks*32 + q4*8 + j]
    short8 qf[4];
#pragma unroll
    for (int ks = 0; ks < 4; ks++)
        qf[ks] = *(const short8*)&Qh[(size_t)(q0 + w * 16 + l15) * 128 + ks * 32 + q4 * 8];

    f32x4 zero = {0.f, 0.f, 0.f, 0.f};
    f32x4 o[8];
#pragma unroll
    for (int ni = 0; ni < 8; ni++) o[ni] = zero;
    float plsum[4] = {0.f, 0.f, 0.f, 0.f};

    for (int kt = 0; kt < 16; kt++) {
        __syncthreads();
        // Ks: phys chunk p in key-row r holds logical chunk l = p ^ (r&15)
#pragma unroll
        for (int i = 0; i < 2; i++) {
            int linear = i * 512 + tid;          // 0..1023, wave-contiguous
            int r = linear >> 4, p = linear & 15;
            int l = p ^ (r & 15);
            gload_lds16(&Kh[(size_t)(kt * 64 + r) * 128 + l * 8], &Ks[linear * 8]);
        }
        // Vt: phys chunk p in d-row holds logical chunk c = p ^ (d&7)
#pragma unroll
        for (int i = 0; i < 2; i++) {
            int linear = i * 512 + tid;          // 0..1023
            int d = linear >> 3, p = linear & 7;
            int c = p ^ (d & 7);
            gload_lds16(&Vh[(size_t)d * 1024 + kt * 64 + c * 8], &Vt[linear * 8]);
        }
        __syncthreads();

        // S = Q K^T : 16q x 64key per wave
        f32x4 sacc[4];
#pragma unroll
        for (int ni = 0; ni < 4; ni++) sacc[ni] = zero;
#pragma unroll
        for (int ks = 0; ks < 4; ks++) {
#pragma unroll
            for (int ni = 0; ni < 4; ni++) {
                int r = ni * 16 + l15;
                int p = (ks * 4 + q4) ^ (r & 15);
                short8 bF = *(const short8*)&Ks[r * 128 + p * 8];
                sacc[ni] = __builtin_amdgcn_mfma_f32_16x16x32_bf16(
                    qf[ks], bF, sacc[ni], 0, 0, 0);
            }
        }

        // P = exp(S) -> Ps (swizzled); accumulate per-lane partial row sums
#pragma unroll
        for (int ni = 0; ni < 4; ni++) {
#pragma unroll
            for (int r = 0; r < 4; r++) {
                float pv = __expf(sacc[ni][r]);
                plsum[r] += pv;
                int qloc = w * 16 + q4 * 4 + r;       // wave-private rows
                int key = ni * 16 + l15;
                int pc = (key >> 3) ^ (qloc & 7);
                Ps[qloc * 64 + pc * 8 + (key & 7)] = f2bf(pv);
            }
        }

        // O += P V  (wave-private Ps rows; same-wave RAW handled by waitcnt)
#pragma unroll
        for (int ks2 = 0; ks2 < 2; ks2++) {
            int c = ks2 * 4 + q4;
            int row = w * 16 + l15;                   // row&7 == l15&7
            short8 aF = *(const short8*)&Ps[row * 64 + (c ^ (l15 & 7)) * 8];
#pragma unroll
            for (int ni = 0; ni < 8; ni++) {
                int d = ni * 16 + l15;
                short8 bF = *(const short8*)&Vt[d * 64 + (c ^ (d & 7)) * 8];
                o[ni] = __builtin_amdgcn_mfma_f32_16x16x32_bf16(aF, bF, o[ni], 0, 0, 0);
            }
        }
    }

    // row sums: reduce per-lane partials over the 16 l15-lanes
#pragma unroll
    for (int r = 0; r < 4; r++) {
#pragma unroll
        for (int m = 1; m < 16; m <<= 1) plsum[r] += __shfl_xor(plsum[r], m, 16);
    }
    float inv[4];
#pragma unroll
    for (int r = 0; r < 4; r++) inv[r] = 1.0f / plsum[r];
#pragma unroll
    for (int ni = 0; ni < 8; ni++)
#pragma unroll
        for (int r = 0; r < 4; r++) {
            int qrow = q0 + w * 16 + q4 * 4 + r;
            ob[(size_t)g * 131072 + (size_t)qrow * 128 + ni * 16 + l15] =
                f2bf(o[ni][r] * inv[r]);
        }
}

// ---------------------------------------------------------------------------
extern "C" void kernel_launch(void* const* d_in, const int* in_sizes, int n_in,
                              void* d_out, int out_size, void* d_ws, size_t ws_size,
                              hipStream_t stream) {
    const float* x     = (const float*)d_in[0];
    const float* ln_g  = (const float*)d_in[1];
    const float* ln_b  = (const float*)d_in[2];
    const float* w_qkv = (const float*)d_in[3];
    const float* b_qkv = (const float*)d_in[4];
    const float* w_out = (const float*)d_in[5];
    const float* b_out = (const float*)d_in[6];
    float* out = (float*)d_out;

    const size_t MC = 8192ull * 1024ull;  // 8.39M elems
    ushort* xn    = (ushort*)d_ws;
    ushort* wqkvT = xn + MC;
    ushort* woutT = wqkvT + 3072ull * 1024ull;
    ushort* qbuf  = woutT + 1024ull * 1024ull;
    ushort* kbuf  = qbuf + MC;
    ushort* vtbuf = kbuf + MC;        // V^T [64 heads][128 d][1024 seq]
    ushort* attnb = vtbuf + MC;       // scratch for raw V, then attn output
    // total: 46.14M ushorts = 92.3 MB (same layout as passing rounds 2-10)

    prep_kernel<<<6144, 256, 0, stream>>>(x, ln_g, ln_b, xn, w_qkv, wqkvT, w_out, woutT);
    // q,k -> qbuf,kbuf ; v -> attnb (scratch, row-major coalesced)
    gemm_qkv<<<1536, 256, 0, stream>>>(xn, wqkvT, b_qkv, qbuf, kbuf, attnb);
    transpose_head<<<dim3(4, 32, 64), 256, 0, stream>>>(attnb, vtbuf);
    attn_kernel<<<512, 512, 0, stream>>>(qbuf, kbuf, vtbuf, attnb);
    gemm_out<<<dim3(8, 128), 256, 0, stream>>>(attnb, woutT, b_out, xn, out);
}